// Round 1
// baseline (35321.182 us; speedup 1.0000x reference)
//
#include <hip/hip_runtime.h>
#include <hip/hip_bf16.h>
#include <math.h>

#define NN 100000
#define NE 1600000
#define NFE 128

// ---------------- aggregation ----------------

__global__ __launch_bounds__(256) void k_init_neg_inf(float* __restrict__ p, int n) {
  int i = blockIdx.x * blockDim.x + threadIdx.x;
  if (i < n) p[i] = __int_as_float(0xFF800000);
}

__device__ __forceinline__ void atomic_max_f(float* a, float v) {
  // exact float max via int ordering; agg initialized to -inf
  if (v >= 0.0f) atomicMax((int*)a, __float_as_int(v));
  else           atomicMin((unsigned int*)a, __float_as_uint(v));
}

__global__ __launch_bounds__(256) void k_scatter_max(const float* __restrict__ h,
                                                     const int* __restrict__ src,
                                                     const int* __restrict__ dst,
                                                     float* __restrict__ agg) {
  long long t = (long long)blockIdx.x * blockDim.x + threadIdx.x;
  int e = (int)(t >> 5);
  if (e >= NE) return;
  int c = ((int)t & 31) << 2;
  int s = src[e], d = dst[e];
  const float4 v = *(const float4*)(h + (size_t)s * NFE + c);
  float* ap = agg + (size_t)d * NFE + c;
  atomic_max_f(ap + 0, v.x);
  atomic_max_f(ap + 1, v.y);
  atomic_max_f(ap + 2, v.z);
  atomic_max_f(ap + 3, v.w);
}

__device__ __forceinline__ float fix_neg_inf(float v) {
  return (__float_as_uint(v) == 0xFF800000u) ? 0.0f : v;
}

__device__ __forceinline__ float leaky(float v) {
  return v >= 0.0f ? v : 0.02f * v;
}

// ---------------- hidden layer: hout = leaky(agg@Wl^T + bl + hin@Wr^T) ----------------

__global__ __launch_bounds__(256) void k_layer(const float* __restrict__ agg,
                                               const float* __restrict__ hin,
                                               const float* __restrict__ Wl,  // [128][128]
                                               const float* __restrict__ bl,  // [128]
                                               const float* __restrict__ Wr,  // [128][128]
                                               float* __restrict__ hout) {
  __shared__ float As[32][132];   // stride 132 -> b128 reads conflict-free
  __shared__ float Hs[32][132];
  const int t = threadIdx.x;
  const int base = blockIdx.x * 32;

  // stage 32x128 tiles of agg (with -inf fix) and hin; 256 thr * 4 float4 each
#pragma unroll
  for (int i = 0; i < 4; ++i) {
    int idx = t + i * 256;         // 1024 float4 per tile
    int n = idx >> 5;              // 32 float4 per row
    int c = (idx & 31) << 2;
    float4 a = *(const float4*)(agg + (size_t)(base + n) * NFE + c);
    a.x = fix_neg_inf(a.x); a.y = fix_neg_inf(a.y);
    a.z = fix_neg_inf(a.z); a.w = fix_neg_inf(a.w);
    *(float4*)(&As[n][c]) = a;
    *(float4*)(&Hs[n][c]) = *(const float4*)(hin + (size_t)(base + n) * NFE + c);
  }
  __syncthreads();

  const int o4 = (t & 31) << 2;    // 4 output channels
  const int n4 = (t >> 5) << 2;    // 4 nodes
  float acc[4][4] = {};            // [out][node]

  // branch 1: agg x Wl
  for (int k = 0; k < NFE; k += 4) {
    float4 a0 = *(const float4*)(&As[n4 + 0][k]);
    float4 a1 = *(const float4*)(&As[n4 + 1][k]);
    float4 a2 = *(const float4*)(&As[n4 + 2][k]);
    float4 a3 = *(const float4*)(&As[n4 + 3][k]);
#pragma unroll
    for (int i = 0; i < 4; ++i) {
      float4 w = *(const float4*)(Wl + (size_t)(o4 + i) * NFE + k);
      acc[i][0] += a0.x * w.x + a0.y * w.y + a0.z * w.z + a0.w * w.w;
      acc[i][1] += a1.x * w.x + a1.y * w.y + a1.z * w.z + a1.w * w.w;
      acc[i][2] += a2.x * w.x + a2.y * w.y + a2.z * w.z + a2.w * w.w;
      acc[i][3] += a3.x * w.x + a3.y * w.y + a3.z * w.z + a3.w * w.w;
    }
  }
  // branch 2: hin x Wr
  for (int k = 0; k < NFE; k += 4) {
    float4 a0 = *(const float4*)(&Hs[n4 + 0][k]);
    float4 a1 = *(const float4*)(&Hs[n4 + 1][k]);
    float4 a2 = *(const float4*)(&Hs[n4 + 2][k]);
    float4 a3 = *(const float4*)(&Hs[n4 + 3][k]);
#pragma unroll
    for (int i = 0; i < 4; ++i) {
      float4 w = *(const float4*)(Wr + (size_t)(o4 + i) * NFE + k);
      acc[i][0] += a0.x * w.x + a0.y * w.y + a0.z * w.z + a0.w * w.w;
      acc[i][1] += a1.x * w.x + a1.y * w.y + a1.z * w.z + a1.w * w.w;
      acc[i][2] += a2.x * w.x + a2.y * w.y + a2.z * w.z + a2.w * w.w;
      acc[i][3] += a3.x * w.x + a3.y * w.y + a3.z * w.z + a3.w * w.w;
    }
  }

  // epilogue: bias + leaky, coalesced float4 stores
  float b0 = bl[o4 + 0], b1 = bl[o4 + 1], b2 = bl[o4 + 2], b3 = bl[o4 + 3];
#pragma unroll
  for (int j = 0; j < 4; ++j) {
    float4 r;
    r.x = leaky(acc[0][j] + b0);
    r.y = leaky(acc[1][j] + b1);
    r.z = leaky(acc[2][j] + b2);
    r.w = leaky(acc[3][j] + b3);
    *(float4*)(hout + (size_t)(base + n4 + j) * NFE + o4) = r;
  }
}

// ---------------- output layer: out = tanh(agg@Wlo^T + blo + h@Wro^T) * 0.5 ----------------

__global__ __launch_bounds__(256) void k_final(const float* __restrict__ agg,
                                               const float* __restrict__ h,
                                               const float* __restrict__ Wlo,  // [3][128]
                                               const float* __restrict__ blo,  // [3]
                                               const float* __restrict__ Wro,  // [3][128]
                                               float* __restrict__ out) {
  int wave = threadIdx.x >> 6;
  int lane = threadIdx.x & 63;
  int n = blockIdx.x * 4 + wave;
  if (n >= NN) return;
  const float* ap = agg + (size_t)n * NFE;
  const float* hp = h + (size_t)n * NFE;
  float a0 = fix_neg_inf(ap[lane]);
  float a1 = fix_neg_inf(ap[lane + 64]);
  float h0 = hp[lane], h1 = hp[lane + 64];
  float p[3];
#pragma unroll
  for (int o = 0; o < 3; ++o) {
    p[o] = a0 * Wlo[o * NFE + lane] + a1 * Wlo[o * NFE + lane + 64]
         + h0 * Wro[o * NFE + lane] + h1 * Wro[o * NFE + lane + 64];
#pragma unroll
    for (int off = 32; off; off >>= 1) p[o] += __shfl_down(p[o], off, 64);
  }
  if (lane == 0) {
#pragma unroll
    for (int o = 0; o < 3; ++o)
      out[(size_t)n * 3 + o] = tanhf(p[o] + blo[o]) * 0.5f;
  }
}

// ---------------- launch ----------------

extern "C" void kernel_launch(void* const* d_in, const int* in_sizes, int n_in,
                              void* d_out, int out_size, void* d_ws, size_t ws_size,
                              hipStream_t stream) {
  const float* x   = (const float*)d_in[0];
  const int*   ei  = (const int*)d_in[1];
  const float* Wl  = (const float*)d_in[2];
  const float* bl  = (const float*)d_in[3];
  const float* Wr  = (const float*)d_in[4];
  const float* Wlo = (const float*)d_in[5];
  const float* blo = (const float*)d_in[6];
  const float* Wro = (const float*)d_in[7];
  float* out = (float*)d_out;

  const int* src = ei;
  const int* dst = ei + NE;

  char* ws = (char*)d_ws;
  const size_t hbytes = (size_t)NN * NFE * sizeof(float);  // 51.2 MB
  float* hA  = (float*)(ws);
  float* hB  = (float*)(ws + hbytes);
  float* agg = (float*)(ws + 2 * hbytes);

  const int aggN = NN * NFE;                       // 12.8M
  const long long sthreads = (long long)NE * 32;   // 51.2M
  const int sblocks = (int)((sthreads + 255) / 256);

  const float* hin = x;
  float* bufs[2] = {hA, hB};
  for (int i = 0; i < 7; ++i) {
    float* hout = bufs[i & 1];
    k_init_neg_inf<<<aggN / 256, 256, 0, stream>>>(agg, aggN);
    k_scatter_max<<<sblocks, 256, 0, stream>>>(hin, src, dst, agg);
    k_layer<<<NN / 32, 256, 0, stream>>>(agg, hin,
                                         Wl + (size_t)i * NFE * NFE,
                                         bl + (size_t)i * NFE,
                                         Wr + (size_t)i * NFE * NFE,
                                         hout);
    hin = hout;
  }

  // final output conv on h7 (= hA after 7 layers)
  k_init_neg_inf<<<aggN / 256, 256, 0, stream>>>(agg, aggN);
  k_scatter_max<<<sblocks, 256, 0, stream>>>(hin, src, dst, agg);
  k_final<<<(NN + 3) / 4, 256, 0, stream>>>(agg, hin, Wlo, blo, Wro, out);
}

// Round 2
// 3996.399 us; speedup vs baseline: 8.8383x; 8.8383x over previous
//
#include <hip/hip_runtime.h>
#include <hip/hip_bf16.h>
#include <math.h>

#define NN 100000
#define NE 1600000
#define NFE 128

// ---------------- CSR build (once per call) ----------------

__global__ __launch_bounds__(256) void k_zero_i32(int* __restrict__ p, int n) {
  int i = blockIdx.x * blockDim.x + threadIdx.x;
  if (i < n) p[i] = 0;
}

__global__ __launch_bounds__(256) void k_hist(const int* __restrict__ dst,
                                              int* __restrict__ counts) {
  int e = blockIdx.x * blockDim.x + threadIdx.x;
  if (e < NE) atomicAdd(&counts[dst[e]], 1);
}

// single-block exclusive scan of counts[NN] -> row_ptr[NN+1]; zeroes cursor
__global__ __launch_bounds__(1024) void k_scan(const int* __restrict__ counts,
                                               int* __restrict__ row_ptr,
                                               int* __restrict__ cursor) {
  __shared__ int sums[1024];
  const int t = threadIdx.x;
  const int CH = (NN + 1023) / 1024;  // 98
  int lo = t * CH, hi = lo + CH; if (hi > NN) hi = NN; if (lo > NN) lo = NN;
  int s = 0;
  for (int i = lo; i < hi; ++i) s += counts[i];
  sums[t] = s;
  __syncthreads();
  // Hillis-Steele inclusive scan
  for (int off = 1; off < 1024; off <<= 1) {
    int v = (t >= off) ? sums[t - off] : 0;
    __syncthreads();
    sums[t] += v;
    __syncthreads();
  }
  int run = (t == 0) ? 0 : sums[t - 1];
  for (int i = lo; i < hi; ++i) {
    row_ptr[i] = run;
    run += counts[i];
    cursor[i] = 0;
  }
  if (t == 0) row_ptr[NN] = NE;
}

__global__ __launch_bounds__(256) void k_fill(const int* __restrict__ src,
                                              const int* __restrict__ dst,
                                              const int* __restrict__ row_ptr,
                                              int* __restrict__ cursor,
                                              int* __restrict__ nbr) {
  int e = blockIdx.x * blockDim.x + threadIdx.x;
  if (e >= NE) return;
  int d = dst[e];
  int p = atomicAdd(&cursor[d], 1);
  nbr[row_ptr[d] + p] = src[e];  // order within row nondeterministic; max is invariant
}

// ---------------- aggregation: gather-max over CSR ----------------

__global__ __launch_bounds__(256) void k_gather_max(const float* __restrict__ h,
                                                    const int* __restrict__ row_ptr,
                                                    const int* __restrict__ nbr,
                                                    float* __restrict__ agg) {
  const int t = threadIdx.x;
  const int n = blockIdx.x * 8 + (t >> 5);  // 8 nodes/block, 32 lanes/node
  const int c = (t & 31) << 2;              // 4 contiguous channels
  const int start = row_ptr[n], end = row_ptr[n + 1];
  const float NI = __int_as_float(0xFF800000);
  float4 acc = make_float4(NI, NI, NI, NI);
  for (int j = start; j < end; ++j) {
    int s = nbr[j];  // wave-broadcast (same addr across the 32-lane group)
    const float4 v = *(const float4*)(h + (size_t)s * NFE + c);
    acc.x = fmaxf(acc.x, v.x); acc.y = fmaxf(acc.y, v.y);
    acc.z = fmaxf(acc.z, v.z); acc.w = fmaxf(acc.w, v.w);
  }
  if (start == end) acc = make_float4(0.f, 0.f, 0.f, 0.f);  // isolated node -> 0
  *(float4*)(agg + (size_t)n * NFE + c) = acc;
}

__device__ __forceinline__ float leaky(float v) {
  return v >= 0.0f ? v : 0.02f * v;
}

// ---------------- hidden layer: hout = leaky(agg@Wl^T + bl + hin@Wr^T) ----------------

__global__ __launch_bounds__(256) void k_layer(const float* __restrict__ agg,
                                               const float* __restrict__ hin,
                                               const float* __restrict__ Wl,  // [128][128]
                                               const float* __restrict__ bl,  // [128]
                                               const float* __restrict__ Wr,  // [128][128]
                                               float* __restrict__ hout) {
  __shared__ float As[32][132];   // stride 132 -> b128 reads conflict-free
  __shared__ float Hs[32][132];
  const int t = threadIdx.x;
  const int base = blockIdx.x * 32;

#pragma unroll
  for (int i = 0; i < 4; ++i) {
    int idx = t + i * 256;         // 1024 float4 per tile
    int n = idx >> 5;              // 32 float4 per row
    int c = (idx & 31) << 2;
    *(float4*)(&As[n][c]) = *(const float4*)(agg + (size_t)(base + n) * NFE + c);
    *(float4*)(&Hs[n][c]) = *(const float4*)(hin + (size_t)(base + n) * NFE + c);
  }
  __syncthreads();

  const int o4 = (t & 31) << 2;    // 4 output channels
  const int n4 = (t >> 5) << 2;    // 4 nodes
  float acc[4][4] = {};            // [out][node]

  for (int k = 0; k < NFE; k += 4) {
    float4 a0 = *(const float4*)(&As[n4 + 0][k]);
    float4 a1 = *(const float4*)(&As[n4 + 1][k]);
    float4 a2 = *(const float4*)(&As[n4 + 2][k]);
    float4 a3 = *(const float4*)(&As[n4 + 3][k]);
#pragma unroll
    for (int i = 0; i < 4; ++i) {
      float4 w = *(const float4*)(Wl + (size_t)(o4 + i) * NFE + k);
      acc[i][0] += a0.x * w.x + a0.y * w.y + a0.z * w.z + a0.w * w.w;
      acc[i][1] += a1.x * w.x + a1.y * w.y + a1.z * w.z + a1.w * w.w;
      acc[i][2] += a2.x * w.x + a2.y * w.y + a2.z * w.z + a2.w * w.w;
      acc[i][3] += a3.x * w.x + a3.y * w.y + a3.z * w.z + a3.w * w.w;
    }
  }
  for (int k = 0; k < NFE; k += 4) {
    float4 a0 = *(const float4*)(&Hs[n4 + 0][k]);
    float4 a1 = *(const float4*)(&Hs[n4 + 1][k]);
    float4 a2 = *(const float4*)(&Hs[n4 + 2][k]);
    float4 a3 = *(const float4*)(&Hs[n4 + 3][k]);
#pragma unroll
    for (int i = 0; i < 4; ++i) {
      float4 w = *(const float4*)(Wr + (size_t)(o4 + i) * NFE + k);
      acc[i][0] += a0.x * w.x + a0.y * w.y + a0.z * w.z + a0.w * w.w;
      acc[i][1] += a1.x * w.x + a1.y * w.y + a1.z * w.z + a1.w * w.w;
      acc[i][2] += a2.x * w.x + a2.y * w.y + a2.z * w.z + a2.w * w.w;
      acc[i][3] += a3.x * w.x + a3.y * w.y + a3.z * w.z + a3.w * w.w;
    }
  }

  float b0 = bl[o4 + 0], b1 = bl[o4 + 1], b2 = bl[o4 + 2], b3 = bl[o4 + 3];
#pragma unroll
  for (int j = 0; j < 4; ++j) {
    float4 r;
    r.x = leaky(acc[0][j] + b0);
    r.y = leaky(acc[1][j] + b1);
    r.z = leaky(acc[2][j] + b2);
    r.w = leaky(acc[3][j] + b3);
    *(float4*)(hout + (size_t)(base + n4 + j) * NFE + o4) = r;
  }
}

// ---------------- output layer: out = tanh(agg@Wlo^T + blo + h@Wro^T) * 0.5 ----------------

__global__ __launch_bounds__(256) void k_final(const float* __restrict__ agg,
                                               const float* __restrict__ h,
                                               const float* __restrict__ Wlo,  // [3][128]
                                               const float* __restrict__ blo,  // [3]
                                               const float* __restrict__ Wro,  // [3][128]
                                               float* __restrict__ out) {
  int wave = threadIdx.x >> 6;
  int lane = threadIdx.x & 63;
  int n = blockIdx.x * 4 + wave;
  if (n >= NN) return;
  const float* ap = agg + (size_t)n * NFE;
  const float* hp = h + (size_t)n * NFE;
  float a0 = ap[lane], a1 = ap[lane + 64];
  float h0 = hp[lane], h1 = hp[lane + 64];
  float p[3];
#pragma unroll
  for (int o = 0; o < 3; ++o) {
    p[o] = a0 * Wlo[o * NFE + lane] + a1 * Wlo[o * NFE + lane + 64]
         + h0 * Wro[o * NFE + lane] + h1 * Wro[o * NFE + lane + 64];
#pragma unroll
    for (int off = 32; off; off >>= 1) p[o] += __shfl_down(p[o], off, 64);
  }
  if (lane == 0) {
#pragma unroll
    for (int o = 0; o < 3; ++o)
      out[(size_t)n * 3 + o] = tanhf(p[o] + blo[o]) * 0.5f;
  }
}

// ---------------- launch ----------------

extern "C" void kernel_launch(void* const* d_in, const int* in_sizes, int n_in,
                              void* d_out, int out_size, void* d_ws, size_t ws_size,
                              hipStream_t stream) {
  const float* x   = (const float*)d_in[0];
  const int*   ei  = (const int*)d_in[1];
  const float* Wl  = (const float*)d_in[2];
  const float* bl  = (const float*)d_in[3];
  const float* Wr  = (const float*)d_in[4];
  const float* Wlo = (const float*)d_in[5];
  const float* blo = (const float*)d_in[6];
  const float* Wro = (const float*)d_in[7];
  float* out = (float*)d_out;

  const int* src = ei;
  const int* dst = ei + NE;

  // workspace layout
  char* ws = (char*)d_ws;
  size_t off = 0;
  auto alloc = [&](size_t bytes) { void* p = ws + off; off = (off + bytes + 255) & ~(size_t)255; return p; };
  int* counts  = (int*)alloc(sizeof(int) * NN);
  int* cursor  = (int*)alloc(sizeof(int) * NN);
  int* row_ptr = (int*)alloc(sizeof(int) * (NN + 1));
  int* nbr     = (int*)alloc(sizeof(int) * NE);
  const size_t hbytes = (size_t)NN * NFE * sizeof(float);  // 51.2 MB
  float* hA  = (float*)alloc(hbytes);
  float* hB  = (float*)alloc(hbytes);
  float* agg = (float*)alloc(hbytes);

  const int EB = (NE + 255) / 256;

  // build CSR (dst-major)
  k_zero_i32<<<(NN + 255) / 256, 256, 0, stream>>>(counts, NN);
  k_hist<<<EB, 256, 0, stream>>>(dst, counts);
  k_scan<<<1, 1024, 0, stream>>>(counts, row_ptr, cursor);
  k_fill<<<EB, 256, 0, stream>>>(src, dst, row_ptr, cursor, nbr);

  const float* hin = x;
  float* bufs[2] = {hA, hB};
  for (int i = 0; i < 7; ++i) {
    float* hout = bufs[i & 1];
    k_gather_max<<<NN / 8, 256, 0, stream>>>(hin, row_ptr, nbr, agg);
    k_layer<<<NN / 32, 256, 0, stream>>>(agg, hin,
                                         Wl + (size_t)i * NFE * NFE,
                                         bl + (size_t)i * NFE,
                                         Wr + (size_t)i * NFE * NFE,
                                         hout);
    hin = hout;
  }

  k_gather_max<<<NN / 8, 256, 0, stream>>>(hin, row_ptr, nbr, agg);
  k_final<<<(NN + 3) / 4, 256, 0, stream>>>(agg, hin, Wlo, blo, Wro, out);
}

// Round 3
// 1827.195 us; speedup vs baseline: 19.3308x; 2.1872x over previous
//
#include <hip/hip_runtime.h>
#include <hip/hip_bf16.h>
#include <math.h>

#define NN 100000
#define NE 1600000
#define NFE 128

using f32x4 = __attribute__((ext_vector_type(4))) float;
using s16x8 = __attribute__((ext_vector_type(8))) short;

__device__ __forceinline__ short bf16_rne(float x) {
  unsigned u = __float_as_uint(x);
  unsigned r = u + 0x7FFFu + ((u >> 16) & 1u);
  return (short)(r >> 16);
}
__device__ __forceinline__ float bf16_f(short s) {
  return __uint_as_float(((unsigned)(unsigned short)s) << 16);
}
__device__ __forceinline__ float leaky(float v) {
  return v >= 0.0f ? v : 0.02f * v;
}

// ---------------- CSR build (once per call) ----------------

__global__ __launch_bounds__(256) void k_zero_i32(int* __restrict__ p, int n) {
  int i = blockIdx.x * blockDim.x + threadIdx.x;
  if (i < n) p[i] = 0;
}

__global__ __launch_bounds__(256) void k_hist(const int* __restrict__ dst,
                                              int* __restrict__ counts) {
  int e = blockIdx.x * blockDim.x + threadIdx.x;
  if (e < NE) atomicAdd(&counts[dst[e]], 1);
}

__global__ __launch_bounds__(1024) void k_scan(const int* __restrict__ counts,
                                               int* __restrict__ row_ptr,
                                               int* __restrict__ cursor) {
  __shared__ int sums[1024];
  const int t = threadIdx.x;
  const int CH = (NN + 1023) / 1024;
  int lo = t * CH, hi = lo + CH; if (hi > NN) hi = NN; if (lo > NN) lo = NN;
  int s = 0;
  for (int i = lo; i < hi; ++i) s += counts[i];
  sums[t] = s;
  __syncthreads();
  for (int off = 1; off < 1024; off <<= 1) {
    int v = (t >= off) ? sums[t - off] : 0;
    __syncthreads();
    sums[t] += v;
    __syncthreads();
  }
  int run = (t == 0) ? 0 : sums[t - 1];
  for (int i = lo; i < hi; ++i) {
    row_ptr[i] = run;
    run += counts[i];
    cursor[i] = 0;
  }
  if (t == 0) row_ptr[NN] = NE;
}

__global__ __launch_bounds__(256) void k_fill(const int* __restrict__ src,
                                              const int* __restrict__ dst,
                                              const int* __restrict__ row_ptr,
                                              int* __restrict__ cursor,
                                              int* __restrict__ nbr) {
  int e = blockIdx.x * blockDim.x + threadIdx.x;
  if (e >= NE) return;
  int d = dst[e];
  int p = atomicAdd(&cursor[d], 1);
  nbr[row_ptr[d] + p] = src[e];  // order within row nondeterministic; max is invariant
}

// ---------------- weight prep: f32 -> bf16 hi/lo, layout [layer][seg][split][out][k] ----------------

__global__ __launch_bounds__(256) void k_prep_w(const float* __restrict__ Wl,
                                                const float* __restrict__ Wr,
                                                short* __restrict__ wb) {
  int idx = blockIdx.x * 256 + threadIdx.x;
  if (idx >= 7 * 2 * 16384) return;
  int li = idx / 32768;
  int rem = idx % 32768;
  int seg = rem / 16384;     // 0 = Wl (agg branch), 1 = Wr (root branch)
  int ok = rem % 16384;      // out*128 + k
  float v = seg ? Wr[li * 16384 + ok] : Wl[li * 16384 + ok];
  short hi = bf16_rne(v);
  short lo = bf16_rne(v - bf16_f(hi));
  short* base = wb + (size_t)li * 65536 + seg * 32768;
  base[ok] = hi;
  base[16384 + ok] = lo;
}

// ---------------- aggregation: gather-max over CSR ----------------

__global__ __launch_bounds__(256) void k_gather_max(const float* __restrict__ h,
                                                    const int* __restrict__ row_ptr,
                                                    const int* __restrict__ nbr,
                                                    float* __restrict__ agg) {
  const int t = threadIdx.x;
  const int n = blockIdx.x * 8 + (t >> 5);
  const int c = (t & 31) << 2;
  const int start = row_ptr[n], end = row_ptr[n + 1];
  const float NI = __int_as_float(0xFF800000);
  float4 acc = make_float4(NI, NI, NI, NI);
  for (int j = start; j < end; ++j) {
    int s = nbr[j];
    const float4 v = *(const float4*)(h + (size_t)s * NFE + c);
    acc.x = fmaxf(acc.x, v.x); acc.y = fmaxf(acc.y, v.y);
    acc.z = fmaxf(acc.z, v.z); acc.w = fmaxf(acc.w, v.w);
  }
  if (start == end) acc = make_float4(0.f, 0.f, 0.f, 0.f);
  *(float4*)(agg + (size_t)n * NFE + c) = acc;
}

// ---------------- hidden layer via split-bf16 MFMA ----------------
// hout = leaky( agg@Wl^T + bl + hin@Wr^T ), each product = Ahi*Whi + Ahi*Wlo + Alo*Whi

__global__ __launch_bounds__(256) void k_layer_mfma(const float* __restrict__ agg,
                                                    const float* __restrict__ hin,
                                                    const short* __restrict__ wbl,  // [4][128][128] hi/lo l/r
                                                    const float* __restrict__ bl,
                                                    float* __restrict__ hout) {
  // LDS: 4 arrays (agg_hi, agg_lo, hin_hi, hin_lo), each 32 rows x 128 k bf16 (8KB)
  // XOR swizzle: byte ^= (row&7)<<4 (applied on both write and read)
  __shared__ __align__(16) char smem[4 * 8192];
  const int t = threadIdx.x;
  const int base = blockIdx.x * 32;

  // stage + convert: 512 chunks of 16B per (hi,lo) pair source; 2 chunks/thread/seg
  for (int seg = 0; seg < 2; ++seg) {
    const float* p = seg ? hin : agg;
    char* dhi = smem + (seg * 2 + 0) * 8192;
    char* dlo = smem + (seg * 2 + 1) * 8192;
#pragma unroll
    for (int i = 0; i < 2; ++i) {
      int c = t + 256 * i;
      int row = c >> 4;
      int kc = (c & 15) * 8;
      const float4* g = (const float4*)(p + (size_t)(base + row) * NFE + kc);
      float4 v0 = g[0], v1 = g[1];
      float f[8] = {v0.x, v0.y, v0.z, v0.w, v1.x, v1.y, v1.z, v1.w};
      s16x8 hv, lv;
#pragma unroll
      for (int j = 0; j < 8; ++j) {
        short h = bf16_rne(f[j]);
        hv[j] = h;
        lv[j] = bf16_rne(f[j] - bf16_f(h));
      }
      int off = row * 256 + kc * 2;
      off ^= (row & 7) << 4;
      *(s16x8*)(dhi + off) = hv;
      *(s16x8*)(dlo + off) = lv;
    }
  }
  __syncthreads();

  const int w = t >> 6;        // wave id: cols 32w..32w+31
  const int l = t & 63;
  const int lr = l & 15;       // row/col within 16-tile
  const int lk = (l >> 4) * 8; // k sub-offset

  f32x4 acc[2][2] = {};        // [row tile][col tile]

#pragma unroll
  for (int seg = 0; seg < 2; ++seg) {
    const char* ahi = smem + (seg * 2 + 0) * 8192;
    const char* alo = smem + (seg * 2 + 1) * 8192;
    const short* bhb = wbl + seg * 32768;          // W hi
    const short* blb = wbl + seg * 32768 + 16384;  // W lo
#pragma unroll
    for (int ks = 0; ks < 4; ++ks) {
      const int k0 = ks * 32;
      int offa0 = (lr) * 256 + (k0 + lk) * 2;      offa0 ^= ((lr) & 7) << 4;
      int offa1 = (16 + lr) * 256 + (k0 + lk) * 2; offa1 ^= ((16 + lr) & 7) << 4;
      s16x8 ah0 = *(const s16x8*)(ahi + offa0);
      s16x8 ah1 = *(const s16x8*)(ahi + offa1);
      s16x8 al0 = *(const s16x8*)(alo + offa0);
      s16x8 al1 = *(const s16x8*)(alo + offa1);
#pragma unroll
      for (int ct = 0; ct < 2; ++ct) {
        const int col = w * 32 + ct * 16 + lr;
        const s16x8 bh = *(const s16x8*)(bhb + col * 128 + k0 + lk);
        const s16x8 bl_ = *(const s16x8*)(blb + col * 128 + k0 + lk);
        acc[0][ct] = __builtin_amdgcn_mfma_f32_16x16x32_bf16(ah0, bh, acc[0][ct], 0, 0, 0);
        acc[1][ct] = __builtin_amdgcn_mfma_f32_16x16x32_bf16(ah1, bh, acc[1][ct], 0, 0, 0);
        acc[0][ct] = __builtin_amdgcn_mfma_f32_16x16x32_bf16(ah0, bl_, acc[0][ct], 0, 0, 0);
        acc[1][ct] = __builtin_amdgcn_mfma_f32_16x16x32_bf16(ah1, bl_, acc[1][ct], 0, 0, 0);
        acc[0][ct] = __builtin_amdgcn_mfma_f32_16x16x32_bf16(al0, bh, acc[0][ct], 0, 0, 0);
        acc[1][ct] = __builtin_amdgcn_mfma_f32_16x16x32_bf16(al1, bh, acc[1][ct], 0, 0, 0);
      }
    }
  }

  // epilogue: bias + leaky; C layout: col = lane&15, row = (lane>>4)*4 + reg
  const float bias0 = bl[w * 32 + lr];
  const float bias1 = bl[w * 32 + 16 + lr];
#pragma unroll
  for (int rt = 0; rt < 2; ++rt) {
#pragma unroll
    for (int r = 0; r < 4; ++r) {
      int node = base + 16 * rt + (l >> 4) * 4 + r;
      float* o = hout + (size_t)node * NFE + w * 32;
      o[lr]      = leaky(acc[rt][0][r] + bias0);
      o[16 + lr] = leaky(acc[rt][1][r] + bias1);
    }
  }
}

// ---------------- output layer ----------------

__global__ __launch_bounds__(256) void k_final(const float* __restrict__ agg,
                                               const float* __restrict__ h,
                                               const float* __restrict__ Wlo,
                                               const float* __restrict__ blo,
                                               const float* __restrict__ Wro,
                                               float* __restrict__ out) {
  int wave = threadIdx.x >> 6;
  int lane = threadIdx.x & 63;
  int n = blockIdx.x * 4 + wave;
  if (n >= NN) return;
  const float* ap = agg + (size_t)n * NFE;
  const float* hp = h + (size_t)n * NFE;
  float a0 = ap[lane], a1 = ap[lane + 64];
  float h0 = hp[lane], h1 = hp[lane + 64];
  float p[3];
#pragma unroll
  for (int o = 0; o < 3; ++o) {
    p[o] = a0 * Wlo[o * NFE + lane] + a1 * Wlo[o * NFE + lane + 64]
         + h0 * Wro[o * NFE + lane] + h1 * Wro[o * NFE + lane + 64];
#pragma unroll
    for (int off = 32; off; off >>= 1) p[o] += __shfl_down(p[o], off, 64);
  }
  if (lane == 0) {
#pragma unroll
    for (int o = 0; o < 3; ++o)
      out[(size_t)n * 3 + o] = tanhf(p[o] + blo[o]) * 0.5f;
  }
}

// ---------------- launch ----------------

extern "C" void kernel_launch(void* const* d_in, const int* in_sizes, int n_in,
                              void* d_out, int out_size, void* d_ws, size_t ws_size,
                              hipStream_t stream) {
  const float* x   = (const float*)d_in[0];
  const int*   ei  = (const int*)d_in[1];
  const float* Wl  = (const float*)d_in[2];
  const float* bl  = (const float*)d_in[3];
  const float* Wr  = (const float*)d_in[4];
  const float* Wlo = (const float*)d_in[5];
  const float* blo = (const float*)d_in[6];
  const float* Wro = (const float*)d_in[7];
  float* out = (float*)d_out;

  const int* src = ei;
  const int* dst = ei + NE;

  char* ws = (char*)d_ws;
  size_t off = 0;
  auto alloc = [&](size_t bytes) { void* p = ws + off; off = (off + bytes + 255) & ~(size_t)255; return p; };
  int* counts  = (int*)alloc(sizeof(int) * NN);
  int* cursor  = (int*)alloc(sizeof(int) * NN);
  int* row_ptr = (int*)alloc(sizeof(int) * (NN + 1));
  int* nbr     = (int*)alloc(sizeof(int) * NE);
  short* wb    = (short*)alloc(sizeof(short) * 7 * 65536);  // 896 KB
  const size_t hbytes = (size_t)NN * NFE * sizeof(float);
  float* hA  = (float*)alloc(hbytes);
  float* hB  = (float*)alloc(hbytes);
  float* agg = (float*)alloc(hbytes);

  const int EB = (NE + 255) / 256;

  k_prep_w<<<(7 * 32768 + 255) / 256, 256, 0, stream>>>(Wl, Wr, wb);
  k_zero_i32<<<(NN + 255) / 256, 256, 0, stream>>>(counts, NN);
  k_hist<<<EB, 256, 0, stream>>>(dst, counts);
  k_scan<<<1, 1024, 0, stream>>>(counts, row_ptr, cursor);
  k_fill<<<EB, 256, 0, stream>>>(src, dst, row_ptr, cursor, nbr);

  const float* hin = x;
  float* bufs[2] = {hA, hB};
  for (int i = 0; i < 7; ++i) {
    float* hout = bufs[i & 1];
    k_gather_max<<<NN / 8, 256, 0, stream>>>(hin, row_ptr, nbr, agg);
    k_layer_mfma<<<NN / 32, 256, 0, stream>>>(agg, hin, wb + (size_t)i * 65536,
                                              bl + (size_t)i * NFE, hout);
    hin = hout;
  }

  k_gather_max<<<NN / 8, 256, 0, stream>>>(hin, row_ptr, nbr, agg);
  k_final<<<(NN + 3) / 4, 256, 0, stream>>>(agg, hin, Wlo, blo, Wro, out);
}

// Round 4
// 1545.910 us; speedup vs baseline: 22.8482x; 1.1820x over previous
//
#include <hip/hip_runtime.h>
#include <hip/hip_bf16.h>
#include <math.h>

#define NN 100000
#define NE 1600000
#define NFE 128
#define SCAN_NB 98   // ceil(NN/1024)

using f32x4 = __attribute__((ext_vector_type(4))) float;
using s16x8 = __attribute__((ext_vector_type(8))) short;

__device__ __forceinline__ short bf16_rne(float x) {
  unsigned u = __float_as_uint(x);
  unsigned r = u + 0x7FFFu + ((u >> 16) & 1u);
  return (short)(r >> 16);
}
__device__ __forceinline__ float bf16_f(short s) {
  return __uint_as_float(((unsigned)(unsigned short)s) << 16);
}
__device__ __forceinline__ float leaky(float v) {
  return v >= 0.0f ? v : 0.02f * v;
}
__device__ __forceinline__ float4 fmax4(float4 a, float4 b) {
  return make_float4(fmaxf(a.x, b.x), fmaxf(a.y, b.y), fmaxf(a.z, b.z), fmaxf(a.w, b.w));
}

// ---------------- CSR build (once per call) ----------------

__global__ __launch_bounds__(256) void k_zero_i32(int* __restrict__ p, int n) {
  int i = blockIdx.x * blockDim.x + threadIdx.x;
  if (i < n) p[i] = 0;
}

__global__ __launch_bounds__(256) void k_hist(const int* __restrict__ dst,
                                              int* __restrict__ counts) {
  int e = blockIdx.x * blockDim.x + threadIdx.x;
  if (e < NE) atomicAdd(&counts[dst[e]], 1);
}

// phase 1: per-block (1024 elems) sums
__global__ __launch_bounds__(256) void k_scan_sum(const int* __restrict__ counts,
                                                  int* __restrict__ bsum) {
  const int t = threadIdx.x;
  const int base = blockIdx.x * 1024 + t * 4;
  int4 c = make_int4(0, 0, 0, 0);
  if (base + 3 < NN) c = *(const int4*)(counts + base);
  else {
    if (base + 0 < NN) c.x = counts[base + 0];
    if (base + 1 < NN) c.y = counts[base + 1];
    if (base + 2 < NN) c.z = counts[base + 2];
  }
  int s = c.x + c.y + c.z + c.w;
#pragma unroll
  for (int off = 32; off; off >>= 1) s += __shfl_down(s, off, 64);
  __shared__ int ws[4];
  if ((t & 63) == 0) ws[t >> 6] = s;
  __syncthreads();
  if (t == 0) bsum[blockIdx.x] = ws[0] + ws[1] + ws[2] + ws[3];
}

// phase 2: scan the 98 block sums (single tiny block)
__global__ __launch_bounds__(128) void k_scan_top(const int* __restrict__ bsum,
                                                  int* __restrict__ boff) {
  __shared__ int v[128];
  const int t = threadIdx.x;
  int mine = (t < SCAN_NB) ? bsum[t] : 0;
  v[t] = mine;
  __syncthreads();
  for (int off = 1; off < 128; off <<= 1) {
    int u = (t >= off) ? v[t - off] : 0;
    __syncthreads();
    v[t] += u;
    __syncthreads();
  }
  if (t < SCAN_NB) boff[t] = v[t] - mine;  // exclusive
}

// phase 3: block-local scan + offset -> row_ptr; zero cursor
__global__ __launch_bounds__(256) void k_scan_blk(const int* __restrict__ counts,
                                                  const int* __restrict__ boff,
                                                  int* __restrict__ row_ptr,
                                                  int* __restrict__ cursor) {
  __shared__ int part[256];
  const int t = threadIdx.x;
  const int base = blockIdx.x * 1024 + t * 4;
  int4 c = make_int4(0, 0, 0, 0);
  if (base + 3 < NN) c = *(const int4*)(counts + base);
  else {
    if (base + 0 < NN) c.x = counts[base + 0];
    if (base + 1 < NN) c.y = counts[base + 1];
    if (base + 2 < NN) c.z = counts[base + 2];
  }
  const int s = c.x + c.y + c.z + c.w;
  part[t] = s;
  __syncthreads();
  for (int off = 1; off < 256; off <<= 1) {
    int u = (t >= off) ? part[t - off] : 0;
    __syncthreads();
    part[t] += u;
    __syncthreads();
  }
  int excl = boff[blockIdx.x] + part[t] - s;
  int4 r;
  r.x = excl;
  r.y = r.x + c.x;
  r.z = r.y + c.y;
  r.w = r.z + c.z;
  const int4 z = make_int4(0, 0, 0, 0);
  if (base + 3 < NN) {
    *(int4*)(row_ptr + base) = r;
    *(int4*)(cursor + base) = z;
  } else {
    if (base + 0 < NN) { row_ptr[base + 0] = r.x; cursor[base + 0] = 0; }
    if (base + 1 < NN) { row_ptr[base + 1] = r.y; cursor[base + 1] = 0; }
    if (base + 2 < NN) { row_ptr[base + 2] = r.z; cursor[base + 2] = 0; }
  }
  if (blockIdx.x == 0 && t == 0) row_ptr[NN] = NE;
}

__global__ __launch_bounds__(256) void k_fill(const int* __restrict__ src,
                                              const int* __restrict__ dst,
                                              const int* __restrict__ row_ptr,
                                              int* __restrict__ cursor,
                                              int* __restrict__ nbr) {
  int e = blockIdx.x * blockDim.x + threadIdx.x;
  if (e >= NE) return;
  int d = dst[e];
  int p = atomicAdd(&cursor[d], 1);
  nbr[row_ptr[d] + p] = src[e];  // order within row nondeterministic; max is invariant
}

// ---------------- weight prep: f32 -> bf16 hi/lo ----------------

__global__ __launch_bounds__(256) void k_prep_w(const float* __restrict__ Wl,
                                                const float* __restrict__ Wr,
                                                short* __restrict__ wb) {
  int idx = blockIdx.x * 256 + threadIdx.x;
  if (idx >= 7 * 2 * 16384) return;
  int li = idx / 32768;
  int rem = idx % 32768;
  int seg = rem / 16384;
  int ok = rem % 16384;
  float v = seg ? Wr[li * 16384 + ok] : Wl[li * 16384 + ok];
  short hi = bf16_rne(v);
  short lo = bf16_rne(v - bf16_f(hi));
  short* base = wb + (size_t)li * 65536 + seg * 32768;
  base[ok] = hi;
  base[16384 + ok] = lo;
}

// ---------------- aggregation: gather-max over CSR, 4-way MLP ----------------

__global__ __launch_bounds__(256) void k_gather_max(const float* __restrict__ h,
                                                    const int* __restrict__ row_ptr,
                                                    const int* __restrict__ nbr,
                                                    float* __restrict__ agg) {
  const int t = threadIdx.x;
  const int n = blockIdx.x * 8 + (t >> 5);
  const int c = (t & 31) << 2;
  const int start = row_ptr[n], end = row_ptr[n + 1];
  const float NI = __int_as_float(0xFF800000);
  float4 acc = make_float4(NI, NI, NI, NI);
  int j = start;
  for (; j + 4 <= end; j += 4) {
    int s0 = nbr[j], s1 = nbr[j + 1], s2 = nbr[j + 2], s3 = nbr[j + 3];
    float4 v0 = *(const float4*)(h + (size_t)s0 * NFE + c);
    float4 v1 = *(const float4*)(h + (size_t)s1 * NFE + c);
    float4 v2 = *(const float4*)(h + (size_t)s2 * NFE + c);
    float4 v3 = *(const float4*)(h + (size_t)s3 * NFE + c);
    acc = fmax4(acc, fmax4(fmax4(v0, v1), fmax4(v2, v3)));
  }
  for (; j < end; ++j) {
    int s = nbr[j];
    acc = fmax4(acc, *(const float4*)(h + (size_t)s * NFE + c));
  }
  if (start == end) acc = make_float4(0.f, 0.f, 0.f, 0.f);
  *(float4*)(agg + (size_t)n * NFE + c) = acc;
}

// ---------------- hidden layer via split-bf16 MFMA ----------------

__global__ __launch_bounds__(256) void k_layer_mfma(const float* __restrict__ agg,
                                                    const float* __restrict__ hin,
                                                    const short* __restrict__ wbl,
                                                    const float* __restrict__ bl,
                                                    float* __restrict__ hout) {
  __shared__ __align__(16) char smem[4 * 8192];
  const int t = threadIdx.x;
  const int base = blockIdx.x * 32;

  for (int seg = 0; seg < 2; ++seg) {
    const float* p = seg ? hin : agg;
    char* dhi = smem + (seg * 2 + 0) * 8192;
    char* dlo = smem + (seg * 2 + 1) * 8192;
#pragma unroll
    for (int i = 0; i < 2; ++i) {
      int c = t + 256 * i;
      int row = c >> 4;
      int kc = (c & 15) * 8;
      const float4* g = (const float4*)(p + (size_t)(base + row) * NFE + kc);
      float4 v0 = g[0], v1 = g[1];
      float f[8] = {v0.x, v0.y, v0.z, v0.w, v1.x, v1.y, v1.z, v1.w};
      s16x8 hv, lv;
#pragma unroll
      for (int j = 0; j < 8; ++j) {
        short h = bf16_rne(f[j]);
        hv[j] = h;
        lv[j] = bf16_rne(f[j] - bf16_f(h));
      }
      int off = row * 256 + kc * 2;
      off ^= (row & 7) << 4;
      *(s16x8*)(dhi + off) = hv;
      *(s16x8*)(dlo + off) = lv;
    }
  }
  __syncthreads();

  const int w = t >> 6;
  const int l = t & 63;
  const int lr = l & 15;
  const int lk = (l >> 4) * 8;

  f32x4 acc[2][2] = {};

#pragma unroll
  for (int seg = 0; seg < 2; ++seg) {
    const char* ahi = smem + (seg * 2 + 0) * 8192;
    const char* alo = smem + (seg * 2 + 1) * 8192;
    const short* bhb = wbl + seg * 32768;
    const short* blb = wbl + seg * 32768 + 16384;
#pragma unroll
    for (int ks = 0; ks < 4; ++ks) {
      const int k0 = ks * 32;
      int offa0 = (lr) * 256 + (k0 + lk) * 2;      offa0 ^= ((lr) & 7) << 4;
      int offa1 = (16 + lr) * 256 + (k0 + lk) * 2; offa1 ^= ((16 + lr) & 7) << 4;
      s16x8 ah0 = *(const s16x8*)(ahi + offa0);
      s16x8 ah1 = *(const s16x8*)(ahi + offa1);
      s16x8 al0 = *(const s16x8*)(alo + offa0);
      s16x8 al1 = *(const s16x8*)(alo + offa1);
#pragma unroll
      for (int ct = 0; ct < 2; ++ct) {
        const int col = w * 32 + ct * 16 + lr;
        const s16x8 bh = *(const s16x8*)(bhb + col * 128 + k0 + lk);
        const s16x8 bl_ = *(const s16x8*)(blb + col * 128 + k0 + lk);
        acc[0][ct] = __builtin_amdgcn_mfma_f32_16x16x32_bf16(ah0, bh, acc[0][ct], 0, 0, 0);
        acc[1][ct] = __builtin_amdgcn_mfma_f32_16x16x32_bf16(ah1, bh, acc[1][ct], 0, 0, 0);
        acc[0][ct] = __builtin_amdgcn_mfma_f32_16x16x32_bf16(ah0, bl_, acc[0][ct], 0, 0, 0);
        acc[1][ct] = __builtin_amdgcn_mfma_f32_16x16x32_bf16(ah1, bl_, acc[1][ct], 0, 0, 0);
        acc[0][ct] = __builtin_amdgcn_mfma_f32_16x16x32_bf16(al0, bh, acc[0][ct], 0, 0, 0);
        acc[1][ct] = __builtin_amdgcn_mfma_f32_16x16x32_bf16(al1, bh, acc[1][ct], 0, 0, 0);
      }
    }
  }

  const float bias0 = bl[w * 32 + lr];
  const float bias1 = bl[w * 32 + 16 + lr];
#pragma unroll
  for (int rt = 0; rt < 2; ++rt) {
#pragma unroll
    for (int r = 0; r < 4; ++r) {
      int node = base + 16 * rt + (l >> 4) * 4 + r;
      float* o = hout + (size_t)node * NFE + w * 32;
      o[lr]      = leaky(acc[rt][0][r] + bias0);
      o[16 + lr] = leaky(acc[rt][1][r] + bias1);
    }
  }
}

// ---------------- output layer ----------------

__global__ __launch_bounds__(256) void k_final(const float* __restrict__ agg,
                                               const float* __restrict__ h,
                                               const float* __restrict__ Wlo,
                                               const float* __restrict__ blo,
                                               const float* __restrict__ Wro,
                                               float* __restrict__ out) {
  int wave = threadIdx.x >> 6;
  int lane = threadIdx.x & 63;
  int n = blockIdx.x * 4 + wave;
  if (n >= NN) return;
  const float* ap = agg + (size_t)n * NFE;
  const float* hp = h + (size_t)n * NFE;
  float a0 = ap[lane], a1 = ap[lane + 64];
  float h0 = hp[lane], h1 = hp[lane + 64];
  float p[3];
#pragma unroll
  for (int o = 0; o < 3; ++o) {
    p[o] = a0 * Wlo[o * NFE + lane] + a1 * Wlo[o * NFE + lane + 64]
         + h0 * Wro[o * NFE + lane] + h1 * Wro[o * NFE + lane + 64];
#pragma unroll
    for (int off = 32; off; off >>= 1) p[o] += __shfl_down(p[o], off, 64);
  }
  if (lane == 0) {
#pragma unroll
    for (int o = 0; o < 3; ++o)
      out[(size_t)n * 3 + o] = tanhf(p[o] + blo[o]) * 0.5f;
  }
}

// ---------------- launch ----------------

extern "C" void kernel_launch(void* const* d_in, const int* in_sizes, int n_in,
                              void* d_out, int out_size, void* d_ws, size_t ws_size,
                              hipStream_t stream) {
  const float* x   = (const float*)d_in[0];
  const int*   ei  = (const int*)d_in[1];
  const float* Wl  = (const float*)d_in[2];
  const float* bl  = (const float*)d_in[3];
  const float* Wr  = (const float*)d_in[4];
  const float* Wlo = (const float*)d_in[5];
  const float* blo = (const float*)d_in[6];
  const float* Wro = (const float*)d_in[7];
  float* out = (float*)d_out;

  const int* src = ei;
  const int* dst = ei + NE;

  char* ws = (char*)d_ws;
  size_t off = 0;
  auto alloc = [&](size_t bytes) { void* p = ws + off; off = (off + bytes + 255) & ~(size_t)255; return p; };
  int* counts  = (int*)alloc(sizeof(int) * NN);
  int* cursor  = (int*)alloc(sizeof(int) * NN);
  int* row_ptr = (int*)alloc(sizeof(int) * (NN + 1));
  int* nbr     = (int*)alloc(sizeof(int) * NE);
  int* bsum    = (int*)alloc(sizeof(int) * 128);
  int* boff    = (int*)alloc(sizeof(int) * 128);
  short* wb    = (short*)alloc(sizeof(short) * 7 * 65536);
  const size_t hbytes = (size_t)NN * NFE * sizeof(float);
  float* hA  = (float*)alloc(hbytes);
  float* hB  = (float*)alloc(hbytes);
  float* agg = (float*)alloc(hbytes);

  const int EB = (NE + 255) / 256;

  k_prep_w<<<(7 * 32768 + 255) / 256, 256, 0, stream>>>(Wl, Wr, wb);
  k_zero_i32<<<(NN + 255) / 256, 256, 0, stream>>>(counts, NN);
  k_hist<<<EB, 256, 0, stream>>>(dst, counts);
  k_scan_sum<<<SCAN_NB, 256, 0, stream>>>(counts, bsum);
  k_scan_top<<<1, 128, 0, stream>>>(bsum, boff);
  k_scan_blk<<<SCAN_NB, 256, 0, stream>>>(counts, boff, row_ptr, cursor);
  k_fill<<<EB, 256, 0, stream>>>(src, dst, row_ptr, cursor, nbr);

  const float* hin = x;
  float* bufs[2] = {hA, hB};
  for (int i = 0; i < 7; ++i) {
    float* hout = bufs[i & 1];
    k_gather_max<<<NN / 8, 256, 0, stream>>>(hin, row_ptr, nbr, agg);
    k_layer_mfma<<<NN / 32, 256, 0, stream>>>(agg, hin, wb + (size_t)i * 65536,
                                              bl + (size_t)i * NFE, hout);
    hin = hout;
  }

  k_gather_max<<<NN / 8, 256, 0, stream>>>(hin, row_ptr, nbr, agg);
  k_final<<<(NN + 3) / 4, 256, 0, stream>>>(agg, hin, Wlo, blo, Wro, out);
}

// Round 5
// 1448.088 us; speedup vs baseline: 24.3916x; 1.0676x over previous
//
#include <hip/hip_runtime.h>
#include <hip/hip_bf16.h>
#include <math.h>

#define NN 100000
#define NE 1600000
#define NFE 128
#define SCAN_NB 98   // ceil(NN/1024)

using f32x4 = __attribute__((ext_vector_type(4))) float;
using s16x8 = __attribute__((ext_vector_type(8))) short;
using s16x4 = __attribute__((ext_vector_type(4))) short;

__device__ __forceinline__ short bf16_rne(float x) {
  unsigned u = __float_as_uint(x);
  unsigned r = u + 0x7FFFu + ((u >> 16) & 1u);
  return (short)(r >> 16);
}
__device__ __forceinline__ float bf16_f(short s) {
  return __uint_as_float(((unsigned)(unsigned short)s) << 16);
}
__device__ __forceinline__ float leaky(float v) {
  return v >= 0.0f ? v : 0.02f * v;
}
__device__ __forceinline__ float4 fmax4(float4 a, float4 b) {
  return make_float4(fmaxf(a.x, b.x), fmaxf(a.y, b.y), fmaxf(a.z, b.z), fmaxf(a.w, b.w));
}

// ---------------- CSR build (once per call) ----------------

__global__ __launch_bounds__(256) void k_zero_i32(int* __restrict__ p, int n) {
  int i = blockIdx.x * blockDim.x + threadIdx.x;
  if (i < n) p[i] = 0;
}

__global__ __launch_bounds__(256) void k_hist(const int* __restrict__ dst,
                                              int* __restrict__ counts) {
  int e = blockIdx.x * blockDim.x + threadIdx.x;
  if (e < NE) atomicAdd(&counts[dst[e]], 1);
}

__global__ __launch_bounds__(256) void k_scan_sum(const int* __restrict__ counts,
                                                  int* __restrict__ bsum) {
  const int t = threadIdx.x;
  const int base = blockIdx.x * 1024 + t * 4;
  int4 c = make_int4(0, 0, 0, 0);
  if (base + 3 < NN) c = *(const int4*)(counts + base);
  else {
    if (base + 0 < NN) c.x = counts[base + 0];
    if (base + 1 < NN) c.y = counts[base + 1];
    if (base + 2 < NN) c.z = counts[base + 2];
  }
  int s = c.x + c.y + c.z + c.w;
#pragma unroll
  for (int off = 32; off; off >>= 1) s += __shfl_down(s, off, 64);
  __shared__ int ws[4];
  if ((t & 63) == 0) ws[t >> 6] = s;
  __syncthreads();
  if (t == 0) bsum[blockIdx.x] = ws[0] + ws[1] + ws[2] + ws[3];
}

__global__ __launch_bounds__(128) void k_scan_top(const int* __restrict__ bsum,
                                                  int* __restrict__ boff) {
  __shared__ int v[128];
  const int t = threadIdx.x;
  int mine = (t < SCAN_NB) ? bsum[t] : 0;
  v[t] = mine;
  __syncthreads();
  for (int off = 1; off < 128; off <<= 1) {
    int u = (t >= off) ? v[t - off] : 0;
    __syncthreads();
    v[t] += u;
    __syncthreads();
  }
  if (t < SCAN_NB) boff[t] = v[t] - mine;  // exclusive
}

__global__ __launch_bounds__(256) void k_scan_blk(const int* __restrict__ counts,
                                                  const int* __restrict__ boff,
                                                  int* __restrict__ row_ptr,
                                                  int* __restrict__ cursor) {
  __shared__ int part[256];
  const int t = threadIdx.x;
  const int base = blockIdx.x * 1024 + t * 4;
  int4 c = make_int4(0, 0, 0, 0);
  if (base + 3 < NN) c = *(const int4*)(counts + base);
  else {
    if (base + 0 < NN) c.x = counts[base + 0];
    if (base + 1 < NN) c.y = counts[base + 1];
    if (base + 2 < NN) c.z = counts[base + 2];
  }
  const int s = c.x + c.y + c.z + c.w;
  part[t] = s;
  __syncthreads();
  for (int off = 1; off < 256; off <<= 1) {
    int u = (t >= off) ? part[t - off] : 0;
    __syncthreads();
    part[t] += u;
    __syncthreads();
  }
  int excl = boff[blockIdx.x] + part[t] - s;
  int4 r;
  r.x = excl;
  r.y = r.x + c.x;
  r.z = r.y + c.y;
  r.w = r.z + c.z;
  const int4 z = make_int4(0, 0, 0, 0);
  if (base + 3 < NN) {
    *(int4*)(row_ptr + base) = r;
    *(int4*)(cursor + base) = z;
  } else {
    if (base + 0 < NN) { row_ptr[base + 0] = r.x; cursor[base + 0] = 0; }
    if (base + 1 < NN) { row_ptr[base + 1] = r.y; cursor[base + 1] = 0; }
    if (base + 2 < NN) { row_ptr[base + 2] = r.z; cursor[base + 2] = 0; }
  }
  if (blockIdx.x == 0 && t == 0) row_ptr[NN] = NE;
}

__global__ __launch_bounds__(256) void k_fill(const int* __restrict__ src,
                                              const int* __restrict__ dst,
                                              const int* __restrict__ row_ptr,
                                              int* __restrict__ cursor,
                                              int* __restrict__ nbr) {
  int e = blockIdx.x * blockDim.x + threadIdx.x;
  if (e >= NE) return;
  int d = dst[e];
  int p = atomicAdd(&cursor[d], 1);
  nbr[row_ptr[d] + p] = src[e];  // order within row nondeterministic; max is invariant
}

// ---------------- weight prep: f32 -> bf16 hi/lo ----------------

__global__ __launch_bounds__(256) void k_prep_w(const float* __restrict__ Wl,
                                                const float* __restrict__ Wr,
                                                short* __restrict__ wb) {
  int idx = blockIdx.x * 256 + threadIdx.x;
  if (idx >= 7 * 2 * 16384) return;
  int li = idx / 32768;
  int rem = idx % 32768;
  int seg = rem / 16384;
  int ok = rem % 16384;
  float v = seg ? Wr[li * 16384 + ok] : Wl[li * 16384 + ok];
  short hi = bf16_rne(v);
  short lo = bf16_rne(v - bf16_f(hi));
  short* base = wb + (size_t)li * 65536 + seg * 32768;
  base[ok] = hi;
  base[16384 + ok] = lo;
}

// ---------------- fused hidden layer: gather-max + split-bf16 MFMA ----------------
// hout = leaky( (max_{s in N(n)} hin[s]) @ Wl^T + bl + hin @ Wr^T )

__global__ __launch_bounds__(256) void k_layer_fused(const float* __restrict__ hin,
                                                     const int* __restrict__ row_ptr,
                                                     const int* __restrict__ nbr,
                                                     const short* __restrict__ wbl,
                                                     const float* __restrict__ bl,
                                                     float* __restrict__ hout) {
  // LDS: 0=agg hi, 1=agg lo, 2=hin hi, 3=hin lo; each 32 rows x 128 k bf16 (8KB)
  // XOR swizzle on byte offsets: off ^= (row&7)<<4 (write and read)
  __shared__ __align__(16) char smem[4 * 8192];
  const int t = threadIdx.x;
  const int base = blockIdx.x * 32;

  // --- stage hin tile (root branch) ---
  {
    char* dhi = smem + 2 * 8192;
    char* dlo = smem + 3 * 8192;
#pragma unroll
    for (int i = 0; i < 2; ++i) {
      int c = t + 256 * i;
      int row = c >> 4;
      int kc = (c & 15) * 8;
      const float4* g = (const float4*)(hin + (size_t)(base + row) * NFE + kc);
      float4 v0 = g[0], v1 = g[1];
      float f[8] = {v0.x, v0.y, v0.z, v0.w, v1.x, v1.y, v1.z, v1.w};
      s16x8 hv, lv;
#pragma unroll
      for (int j = 0; j < 8; ++j) {
        short h = bf16_rne(f[j]);
        hv[j] = h;
        lv[j] = bf16_rne(f[j] - bf16_f(h));
      }
      int off = row * 256 + kc * 2;
      off ^= (row & 7) << 4;
      *(s16x8*)(dhi + off) = hv;
      *(s16x8*)(dlo + off) = lv;
    }
  }

  // --- gather-max directly into the A tile (neighbor branch) ---
  {
    char* ahi = smem;
    char* alo = smem + 8192;
    const int grp = t >> 5;        // 8 groups of 32 lanes
    const int lg = t & 31;
    const int c4 = lg << 2;        // 4 contiguous channels
    const float NI = __int_as_float(0xFF800000);
#pragma unroll
    for (int ni = 0; ni < 4; ++ni) {
      const int r = grp * 4 + ni;  // in-block row
      const int n = base + r;
      const int start = row_ptr[n], end = row_ptr[n + 1];
      float4 acc = make_float4(NI, NI, NI, NI);
      int j = start;
      for (; j + 4 <= end; j += 4) {
        int s0 = nbr[j], s1 = nbr[j + 1], s2 = nbr[j + 2], s3 = nbr[j + 3];
        float4 v0 = *(const float4*)(hin + (size_t)s0 * NFE + c4);
        float4 v1 = *(const float4*)(hin + (size_t)s1 * NFE + c4);
        float4 v2 = *(const float4*)(hin + (size_t)s2 * NFE + c4);
        float4 v3 = *(const float4*)(hin + (size_t)s3 * NFE + c4);
        acc = fmax4(acc, fmax4(fmax4(v0, v1), fmax4(v2, v3)));
      }
      for (; j < end; ++j) {
        int s = nbr[j];
        acc = fmax4(acc, *(const float4*)(hin + (size_t)s * NFE + c4));
      }
      if (start == end) acc = make_float4(0.f, 0.f, 0.f, 0.f);
      float f[4] = {acc.x, acc.y, acc.z, acc.w};
      s16x4 hv, lv;
#pragma unroll
      for (int q = 0; q < 4; ++q) {
        short h = bf16_rne(f[q]);
        hv[q] = h;
        lv[q] = bf16_rne(f[q] - bf16_f(h));
      }
      int off = r * 256 + c4 * 2;
      off ^= (r & 7) << 4;
      *(s16x4*)(ahi + off) = hv;
      *(s16x4*)(alo + off) = lv;
    }
  }
  __syncthreads();

  // --- split-bf16 MFMA: Ahi*Whi + Ahi*Wlo + Alo*Whi per branch ---
  const int w = t >> 6;
  const int l = t & 63;
  const int lr = l & 15;
  const int lk = (l >> 4) * 8;

  f32x4 acc[2][2] = {};

#pragma unroll
  for (int seg = 0; seg < 2; ++seg) {
    const char* ahi = smem + (seg * 2 + 0) * 8192;
    const char* alo = smem + (seg * 2 + 1) * 8192;
    const short* bhb = wbl + seg * 32768;
    const short* blb = wbl + seg * 32768 + 16384;
#pragma unroll
    for (int ks = 0; ks < 4; ++ks) {
      const int k0 = ks * 32;
      int offa0 = (lr) * 256 + (k0 + lk) * 2;      offa0 ^= ((lr) & 7) << 4;
      int offa1 = (16 + lr) * 256 + (k0 + lk) * 2; offa1 ^= ((16 + lr) & 7) << 4;
      s16x8 ah0 = *(const s16x8*)(ahi + offa0);
      s16x8 ah1 = *(const s16x8*)(ahi + offa1);
      s16x8 al0 = *(const s16x8*)(alo + offa0);
      s16x8 al1 = *(const s16x8*)(alo + offa1);
#pragma unroll
      for (int ct = 0; ct < 2; ++ct) {
        const int col = w * 32 + ct * 16 + lr;
        const s16x8 bh = *(const s16x8*)(bhb + col * 128 + k0 + lk);
        const s16x8 bl_ = *(const s16x8*)(blb + col * 128 + k0 + lk);
        acc[0][ct] = __builtin_amdgcn_mfma_f32_16x16x32_bf16(ah0, bh, acc[0][ct], 0, 0, 0);
        acc[1][ct] = __builtin_amdgcn_mfma_f32_16x16x32_bf16(ah1, bh, acc[1][ct], 0, 0, 0);
        acc[0][ct] = __builtin_amdgcn_mfma_f32_16x16x32_bf16(ah0, bl_, acc[0][ct], 0, 0, 0);
        acc[1][ct] = __builtin_amdgcn_mfma_f32_16x16x32_bf16(ah1, bl_, acc[1][ct], 0, 0, 0);
        acc[0][ct] = __builtin_amdgcn_mfma_f32_16x16x32_bf16(al0, bh, acc[0][ct], 0, 0, 0);
        acc[1][ct] = __builtin_amdgcn_mfma_f32_16x16x32_bf16(al1, bh, acc[1][ct], 0, 0, 0);
      }
    }
  }

  const float bias0 = bl[w * 32 + lr];
  const float bias1 = bl[w * 32 + 16 + lr];
#pragma unroll
  for (int rt = 0; rt < 2; ++rt) {
#pragma unroll
    for (int r = 0; r < 4; ++r) {
      int node = base + 16 * rt + (l >> 4) * 4 + r;
      float* o = hout + (size_t)node * NFE + w * 32;
      o[lr]      = leaky(acc[rt][0][r] + bias0);
      o[16 + lr] = leaky(acc[rt][1][r] + bias1);
    }
  }
}

// ---------------- fused output layer: gather-max + tiny GEMV + tanh ----------------

__global__ __launch_bounds__(256) void k_final_fused(const float* __restrict__ h,
                                                     const int* __restrict__ row_ptr,
                                                     const int* __restrict__ nbr,
                                                     const float* __restrict__ Wlo,
                                                     const float* __restrict__ blo,
                                                     const float* __restrict__ Wro,
                                                     float* __restrict__ out) {
  const int wave = threadIdx.x >> 6;
  const int lane = threadIdx.x & 63;
  const int n = blockIdx.x * 4 + wave;
  if (n >= NN) return;
  const int c2 = lane * 2;
  const int start = row_ptr[n], end = row_ptr[n + 1];
  const float NI = __int_as_float(0xFF800000);
  float ax = NI, ay = NI;
  int j = start;
  for (; j + 4 <= end; j += 4) {
    int s0 = nbr[j], s1 = nbr[j + 1], s2 = nbr[j + 2], s3 = nbr[j + 3];
    float2 v0 = *(const float2*)(h + (size_t)s0 * NFE + c2);
    float2 v1 = *(const float2*)(h + (size_t)s1 * NFE + c2);
    float2 v2 = *(const float2*)(h + (size_t)s2 * NFE + c2);
    float2 v3 = *(const float2*)(h + (size_t)s3 * NFE + c2);
    ax = fmaxf(ax, fmaxf(fmaxf(v0.x, v1.x), fmaxf(v2.x, v3.x)));
    ay = fmaxf(ay, fmaxf(fmaxf(v0.y, v1.y), fmaxf(v2.y, v3.y)));
  }
  for (; j < end; ++j) {
    float2 v = *(const float2*)(h + (size_t)nbr[j] * NFE + c2);
    ax = fmaxf(ax, v.x);
    ay = fmaxf(ay, v.y);
  }
  if (start == end) { ax = 0.f; ay = 0.f; }
  const float2 hv = *(const float2*)(h + (size_t)n * NFE + c2);
  float p[3];
#pragma unroll
  for (int o = 0; o < 3; ++o) {
    const float2 wl = *(const float2*)(Wlo + o * NFE + c2);
    const float2 wr = *(const float2*)(Wro + o * NFE + c2);
    p[o] = ax * wl.x + ay * wl.y + hv.x * wr.x + hv.y * wr.y;
#pragma unroll
    for (int off = 32; off; off >>= 1) p[o] += __shfl_down(p[o], off, 64);
  }
  if (lane == 0) {
#pragma unroll
    for (int o = 0; o < 3; ++o)
      out[(size_t)n * 3 + o] = tanhf(p[o] + blo[o]) * 0.5f;
  }
}

// ---------------- launch ----------------

extern "C" void kernel_launch(void* const* d_in, const int* in_sizes, int n_in,
                              void* d_out, int out_size, void* d_ws, size_t ws_size,
                              hipStream_t stream) {
  const float* x   = (const float*)d_in[0];
  const int*   ei  = (const int*)d_in[1];
  const float* Wl  = (const float*)d_in[2];
  const float* bl  = (const float*)d_in[3];
  const float* Wr  = (const float*)d_in[4];
  const float* Wlo = (const float*)d_in[5];
  const float* blo = (const float*)d_in[6];
  const float* Wro = (const float*)d_in[7];
  float* out = (float*)d_out;

  const int* src = ei;
  const int* dst = ei + NE;

  char* ws = (char*)d_ws;
  size_t off = 0;
  auto alloc = [&](size_t bytes) { void* p = ws + off; off = (off + bytes + 255) & ~(size_t)255; return p; };
  int* counts  = (int*)alloc(sizeof(int) * NN);
  int* cursor  = (int*)alloc(sizeof(int) * NN);
  int* row_ptr = (int*)alloc(sizeof(int) * (NN + 1));
  int* nbr     = (int*)alloc(sizeof(int) * NE);
  int* bsum    = (int*)alloc(sizeof(int) * 128);
  int* boff    = (int*)alloc(sizeof(int) * 128);
  short* wb    = (short*)alloc(sizeof(short) * 7 * 65536);
  const size_t hbytes = (size_t)NN * NFE * sizeof(float);
  float* hA  = (float*)alloc(hbytes);
  float* hB  = (float*)alloc(hbytes);

  const int EB = (NE + 255) / 256;

  k_prep_w<<<(7 * 32768 + 255) / 256, 256, 0, stream>>>(Wl, Wr, wb);
  k_zero_i32<<<(NN + 255) / 256, 256, 0, stream>>>(counts, NN);
  k_hist<<<EB, 256, 0, stream>>>(dst, counts);
  k_scan_sum<<<SCAN_NB, 256, 0, stream>>>(counts, bsum);
  k_scan_top<<<1, 128, 0, stream>>>(bsum, boff);
  k_scan_blk<<<SCAN_NB, 256, 0, stream>>>(counts, boff, row_ptr, cursor);
  k_fill<<<EB, 256, 0, stream>>>(src, dst, row_ptr, cursor, nbr);

  const float* hin = x;
  float* bufs[2] = {hA, hB};
  for (int i = 0; i < 7; ++i) {
    float* hout = bufs[i & 1];
    k_layer_fused<<<NN / 32, 256, 0, stream>>>(hin, row_ptr, nbr,
                                               wb + (size_t)i * 65536,
                                               bl + (size_t)i * NFE, hout);
    hin = hout;
  }

  k_final_fused<<<(NN + 3) / 4, 256, 0, stream>>>(hin, row_ptr, nbr, Wlo, blo, Wro, out);
}